// Round 11
// baseline (416.614 us; speedup 1.0000x reference)
//
#include <hip/hip_runtime.h>

#define NN 50000
#define NE 800000
#define FIN 500
#define DH 128
#define NC 10

typedef __attribute__((ext_vector_type(8))) short short8v;   // 8 bf16 (4 VGPRs)
typedef __attribute__((ext_vector_type(4))) float float4v;   // MFMA C/D
typedef __attribute__((ext_vector_type(4))) int int4v;

__device__ __forceinline__ ushort f32_bf16_rne(float f) {
    uint u = __float_as_uint(f);
    uint r = u + 0x7FFFu + ((u >> 16) & 1u);
    return (ushort)(r >> 16);
}

// split 8 f32 -> bf16 hi + bf16 lo via v_cvt_pk_bf16_f32 (RNE, 2 elems/inst)
__device__ __forceinline__ void split8(const float f[8], short8v& hi, short8v& lo) {
    int4v hw, lw;
    #pragma unroll
    for (int p = 0; p < 4; ++p) {
        float x0 = f[2 * p], x1 = f[2 * p + 1];
        uint h;
        asm("v_cvt_pk_bf16_f32 %0, %1, %2" : "=v"(h) : "v"(x0), "v"(x1));
        float r0 = x0 - __uint_as_float(h << 16);
        float r1 = x1 - __uint_as_float(h & 0xFFFF0000u);
        uint l;
        asm("v_cvt_pk_bf16_f32 %0, %1, %2" : "=v"(l) : "v"(r0), "v"(r1));
        hw[p] = (int)h; lw[p] = (int)l;
    }
    hi = __builtin_bit_cast(short8v, hw);
    lo = __builtin_bit_cast(short8v, lw);
}

// ---------------- setup kernels ----------------

__global__ void init_packed_kernel(unsigned long long* __restrict__ packed, int n) {
    int i = blockIdx.x * blockDim.x + threadIdx.x;
    if (i < n) packed[i] = 0ULL;
}

// ONE 64-bit atomic per edge: high word = incoming-edge count, low word = sum of
// w in 24-bit fixed point. Returned old high word = edge's rank within dst row.
__global__ void deg_rank_kernel(const int* __restrict__ ei, const float* __restrict__ w,
                                unsigned long long* __restrict__ packed,
                                uint* __restrict__ rank, int e) {
    int i = blockIdx.x * blockDim.x + threadIdx.x;
    if (i < e) {
        int d = ei[NE + i];
        uint fx = (uint)(w[i] * 16777216.0f + 0.5f);
        unsigned long long old = atomicAdd(&packed[d], (1ULL << 32) | (unsigned long long)fx);
        rank[i] = (uint)(old >> 32);
    }
}

// deg = 1 (self-loop) + fixed-point sum; dinv = rsqrt(deg)
__global__ void unpack_kernel(const unsigned long long* __restrict__ packed,
                              float* __restrict__ dinv, int n) {
    int i = blockIdx.x * blockDim.x + threadIdx.x;
    if (i < n) {
        float deg = 1.0f + (float)(uint)packed[i] * (1.0f / 16777216.0f);
        dinv[i] = rsqrtf(deg);
    }
}

// ---- 3-phase scan over counts (high words of packed) -> rowptr (exclusive) ----
__global__ void scan1_kernel(const unsigned long long* __restrict__ packed,
                             int* __restrict__ rp, int* __restrict__ bsum, int n) {
    __shared__ int sw[4];
    int t = threadIdx.x, lane = t & 63, w = t >> 6;
    int base = blockIdx.x * 1024 + t * 4;
    int c0 = (base + 0 < n) ? (int)(packed[base + 0] >> 32) : 0;
    int c1 = (base + 1 < n) ? (int)(packed[base + 1] >> 32) : 0;
    int c2 = (base + 2 < n) ? (int)(packed[base + 2] >> 32) : 0;
    int c3 = (base + 3 < n) ? (int)(packed[base + 3] >> 32) : 0;
    int s0 = c0, s1 = s0 + c1, s2 = s1 + c2, s3 = s2 + c3;
    int x = s3;
    #pragma unroll
    for (int off = 1; off < 64; off <<= 1) {
        int y = __shfl_up(x, off, 64);
        if (lane >= off) x += y;
    }
    if (lane == 63) sw[w] = x;
    __syncthreads();
    int woff = 0;
    for (int j = 0; j < w; ++j) woff += sw[j];
    int excl = woff + x - s3;
    if (base + 0 < n) rp[base + 0] = excl;
    if (base + 1 < n) rp[base + 1] = excl + s0;
    if (base + 2 < n) rp[base + 2] = excl + s1;
    if (base + 3 < n) rp[base + 3] = excl + s2;
    if (t == 255) bsum[blockIdx.x] = woff + x;
}

__global__ void scan2_kernel(int* __restrict__ bsum, int nb) {
    int lane = threadIdx.x;
    int v = (lane < nb) ? bsum[lane] : 0;
    int x = v;
    #pragma unroll
    for (int off = 1; off < 64; off <<= 1) {
        int y = __shfl_up(x, off, 64);
        if (lane >= off) x += y;
    }
    if (lane < nb) bsum[lane] = x - v;
}

__global__ void scan3_kernel(int* __restrict__ rp, const int* __restrict__ bsum, int n) {
    int i = blockIdx.x * blockDim.x + threadIdx.x;
    if (i < n) rp[i] = rp[i] + bsum[i >> 10];
    if (i == 0) rp[n] = NE;
}

// atomic-free scatter: pos = rowptr[d] + rank; ONE 8B store per edge (int2{src,norm})
__global__ void scatter_kernel(const int* __restrict__ ei, const float* __restrict__ w,
                               const float* __restrict__ dinv, const uint* __restrict__ rank,
                               const int* __restrict__ rowptr,
                               int2* __restrict__ csr, int e) {
    int i = blockIdx.x * blockDim.x + threadIdx.x;
    if (i < e) {
        int s = ei[i];
        int d = ei[NE + i];
        int pos = rowptr[d] + (int)rank[i];
        float nm = dinv[s] * w[i] * dinv[d];
        csr[pos] = make_int2(s, __float_as_int(nm));
    }
}

// ---- prep: W[K][128] -> Bf in MFMA fragment order ----
__global__ void prep_w_kernel(const float* __restrict__ W, ushort* __restrict__ Bf,
                              int K, int total) {
    int idx = blockIdx.x * blockDim.x + threadIdx.x;
    if (idx >= total) return;
    int j = idx & 7;
    int lane = (idx >> 3) & 63;
    int h = (idx >> 9) & 1;
    int c = (idx >> 10) & 7;
    int ks = idx >> 13;
    int k = ks * 32 + (lane >> 4) * 8 + j;
    int col = c * 16 + (lane & 15);
    float v = (k < K) ? W[k * DH + col] : 0.f;
    ushort hi = f32_bf16_rne(v);
    ushort o;
    if (h == 0) o = hi;
    else {
        float hf = __uint_as_float((uint)hi << 16);
        o = f32_bf16_rne(v - hf);
    }
    Bf[idx] = o;
}

// ---------------- MFMA matmul (unchanged from round 8) ----------------

__device__ __forceinline__ void load_split_row(const float* __restrict__ Af, int row, int kb,
                                               int K, bool last, short8v& hi, short8v& lo) {
    float f[8];
    if (last && kb + 8 > K) {
        #pragma unroll
        for (int j = 0; j < 8; ++j)
            f[j] = (kb + j < K) ? Af[(size_t)row * K + kb + j] : 0.f;
    } else {
        float4 t0 = *(const float4*)(Af + (size_t)row * K + kb);
        float4 t1 = *(const float4*)(Af + (size_t)row * K + kb + 4);
        f[0] = t0.x; f[1] = t0.y; f[2] = t0.z; f[3] = t0.w;
        f[4] = t1.x; f[5] = t1.y; f[6] = t1.z; f[7] = t1.w;
    }
    split8(f, hi, lo);
}

template<int A_SPLIT>
__global__ __launch_bounds__(256)
void mm_mfma_kernel(const float* __restrict__ Af,
                    const ushort* __restrict__ Ah, const ushort* __restrict__ Al,
                    const ushort* __restrict__ Bf,
                    float* __restrict__ C, int M, int K, int Kp) {
    __shared__ ushort Bs[4 * 8192];
    const int t = threadIdx.x;
    const int lane = t & 63, wid = t >> 6;
    const int lrow = lane & 15, lk = lane >> 4;
    const int row0 = blockIdx.x * 128 + wid * 32;
    const int nchunks = Kp >> 7;

    float4v acc0[8], acc1[8];
    #pragma unroll
    for (int c = 0; c < 8; ++c) {
        acc0[c] = (float4v){0.f, 0.f, 0.f, 0.f};
        acc1[c] = (float4v){0.f, 0.f, 0.f, 0.f};
    }

    int ar0 = row0 + lrow;       if (ar0 > M - 1) ar0 = M - 1;
    int ar1 = row0 + 16 + lrow;  if (ar1 > M - 1) ar1 = M - 1;
    const bool l0 = (ar0 == M - 1), l1 = (ar1 == M - 1);

    for (int kc = 0; kc < nchunks; ++kc) {
        const uint4* src = (const uint4*)(Bf + (size_t)kc * 32768);
        #pragma unroll
        for (int i = 0; i < 16; ++i) {
            int slot = i * 256 + t;
            *(uint4*)&Bs[slot * 8] = src[slot];
        }
        __syncthreads();
        #pragma unroll
        for (int ksl = 0; ksl < 4; ++ksl) {
            const int kb = (kc * 4 + ksl) * 32 + lk * 8;
            short8v a0h, a0l, a1h, a1l;
            if (A_SPLIT) {
                a0h = *(const short8v*)(Ah + (size_t)ar0 * Kp + kb);
                a0l = *(const short8v*)(Al + (size_t)ar0 * Kp + kb);
                a1h = *(const short8v*)(Ah + (size_t)ar1 * Kp + kb);
                a1l = *(const short8v*)(Al + (size_t)ar1 * Kp + kb);
            } else {
                load_split_row(Af, ar0, kb, K, l0, a0h, a0l);
                load_split_row(Af, ar1, kb, K, l1, a1h, a1l);
            }
            const ushort* bp = &Bs[ksl * 8192 + lane * 8];
            #pragma unroll
            for (int c = 0; c < 8; ++c) {
                short8v bh = *(const short8v*)(bp + c * 1024);
                short8v bl = *(const short8v*)(bp + c * 1024 + 512);
                acc0[c] = __builtin_amdgcn_mfma_f32_16x16x32_bf16(a0h, bh, acc0[c], 0, 0, 0);
                acc0[c] = __builtin_amdgcn_mfma_f32_16x16x32_bf16(a0h, bl, acc0[c], 0, 0, 0);
                acc0[c] = __builtin_amdgcn_mfma_f32_16x16x32_bf16(a0l, bh, acc0[c], 0, 0, 0);
                acc1[c] = __builtin_amdgcn_mfma_f32_16x16x32_bf16(a1h, bh, acc1[c], 0, 0, 0);
                acc1[c] = __builtin_amdgcn_mfma_f32_16x16x32_bf16(a1h, bl, acc1[c], 0, 0, 0);
                acc1[c] = __builtin_amdgcn_mfma_f32_16x16x32_bf16(a1l, bh, acc1[c], 0, 0, 0);
            }
        }
        __syncthreads();
    }
    #pragma unroll
    for (int c = 0; c < 8; ++c) {
        #pragma unroll
        for (int j = 0; j < 4; ++j) {
            int r0 = row0 + lk * 4 + j;
            int r1 = row0 + 16 + lk * 4 + j;
            if (r0 < M) C[(size_t)r0 * DH + c * 16 + lrow] = acc0[c][j];
            if (r1 < M) C[(size_t)r1 * DH + c * 16 + lrow] = acc1[c][j];
        }
    }
}

// ---------------- aggregation: wave per node, 2 edges per dwordx4 gather ------
// lane = half*32 + fl: lane covers features fl*4..fl*4+3 of its half's edge.
// Main loop 8 edges/iter: 8 unmasked int2 metadata loads + 4 dwordx4 gathers.
// Halves combined at the end with one shfl_xor(32). Self-loop in half 0 only.

#define AGG_BODY                                                                  \
    int node = (blockIdx.x * 256 + threadIdx.x) >> 6;                             \
    if (node >= n) return;                                                        \
    int lane = threadIdx.x & 63;                                                  \
    int half = lane >> 5, fl = lane & 31;                                         \
    const float4* __restrict__ h4 = (const float4*)h;                             \
    float di = dinv[node];                                                        \
    float4 acc = make_float4(0.f, 0.f, 0.f, 0.f);                                 \
    if (half == 0) {                                                              \
        float4 hv = h4[(size_t)node * 32 + fl];                                   \
        float d2 = di * di;                                                       \
        acc.x = d2 * hv.x; acc.y = d2 * hv.y;                                     \
        acc.z = d2 * hv.z; acc.w = d2 * hv.w;                                     \
    }                                                                             \
    int e = rowptr[node], e1 = rowptr[node + 1];                                  \
    for (; e + 8 <= e1; e += 8) {                                                 \
        int2 m[8];                                                                \
        _Pragma("unroll")                                                         \
        for (int j = 0; j < 8; ++j) m[j] = csr[e + j];                            \
        _Pragma("unroll")                                                         \
        for (int p = 0; p < 4; ++p) {                                             \
            int  sidx = half ? m[2 * p + 1].x : m[2 * p].x;                       \
            float nm  = __int_as_float(half ? m[2 * p + 1].y : m[2 * p].y);       \
            float4 v = h4[(size_t)sidx * 32 + fl];                                \
            acc.x = fmaf(nm, v.x, acc.x); acc.y = fmaf(nm, v.y, acc.y);           \
            acc.z = fmaf(nm, v.z, acc.z); acc.w = fmaf(nm, v.w, acc.w);           \
        }                                                                         \
    }                                                                             \
    for (; e < e1; e += 2) {                                                      \
        int eidx = e + half;                                                      \
        bool valid = eidx < e1;                                                   \
        int2 pr = csr[valid ? eidx : e1 - 1];                                     \
        float nm = valid ? __int_as_float(pr.y) : 0.f;                            \
        float4 v = h4[(size_t)pr.x * 32 + fl];                                    \
        acc.x = fmaf(nm, v.x, acc.x); acc.y = fmaf(nm, v.y, acc.y);               \
        acc.z = fmaf(nm, v.z, acc.z); acc.w = fmaf(nm, v.w, acc.w);               \
    }                                                                             \
    acc.x += __shfl_xor(acc.x, 32, 64);                                           \
    acc.y += __shfl_xor(acc.y, 32, 64);                                           \
    acc.z += __shfl_xor(acc.z, 32, 64);                                           \
    acc.w += __shfl_xor(acc.w, 32, 64);                                           \
    float4 bv = *(const float4*)&bias[fl * 4];                                    \
    float rx = fmaxf(acc.x + bv.x, 0.f), ry = fmaxf(acc.y + bv.y, 0.f);           \
    float rz = fmaxf(acc.z + bv.z, 0.f), rw = fmaxf(acc.w + bv.w, 0.f);

__global__ __launch_bounds__(256)
void agg_bf16_kernel(const float* __restrict__ h, const int* __restrict__ rowptr,
                     const int2* __restrict__ csr,
                     const float* __restrict__ dinv, const float* __restrict__ bias,
                     ushort* __restrict__ oh, ushort* __restrict__ ol, int n) {
    AGG_BODY
    if (half == 0) {
        float f[4] = {rx, ry, rz, rw};
        ushort hh[4], ll[4];
        #pragma unroll
        for (int j = 0; j < 4; ++j) {
            hh[j] = f32_bf16_rne(f[j]);
            ll[j] = f32_bf16_rne(f[j] - __uint_as_float((uint)hh[j] << 16));
        }
        *(ushort4*)&oh[(size_t)node * DH + fl * 4] = make_ushort4(hh[0], hh[1], hh[2], hh[3]);
        *(ushort4*)&ol[(size_t)node * DH + fl * 4] = make_ushort4(ll[0], ll[1], ll[2], ll[3]);
    }
}

// agg + classifier fused
__global__ __launch_bounds__(256)
void agg_cls_kernel(const float* __restrict__ h, const int* __restrict__ rowptr,
                    const int2* __restrict__ csr,
                    const float* __restrict__ dinv, const float* __restrict__ bias,
                    const float* __restrict__ Wc, const float* __restrict__ bc,
                    float* __restrict__ out, int n) {
    AGG_BODY
    float myv = 0.f;
    #pragma unroll
    for (int c = 0; c < NC; ++c) {
        float p = rx * Wc[(fl * 4 + 0) * NC + c] + ry * Wc[(fl * 4 + 1) * NC + c]
                + rz * Wc[(fl * 4 + 2) * NC + c] + rw * Wc[(fl * 4 + 3) * NC + c];
        p = half ? 0.f : p;            // halves duplicate after combine: count once
        p += __shfl_xor(p, 32, 64);
        p += __shfl_xor(p, 16, 64);
        p += __shfl_xor(p, 8, 64);
        p += __shfl_xor(p, 4, 64);
        p += __shfl_xor(p, 2, 64);
        p += __shfl_xor(p, 1, 64);
        if (lane == c) myv = p;
    }
    if (lane < NC) out[(size_t)node * NC + lane] = myv + bc[lane];
}

// ---------------- launch ----------------

extern "C" void kernel_launch(void* const* d_in, const int* in_sizes, int n_in,
                              void* d_out, int out_size, void* d_ws, size_t ws_size,
                              hipStream_t stream) {
    const float* x  = (const float*)d_in[0];
    const int*   ei = (const int*)d_in[1];
    const float* ew = (const float*)d_in[2];
    const float* W1 = (const float*)d_in[3];
    const float* b1 = (const float*)d_in[4];
    const float* W2 = (const float*)d_in[5];
    const float* b2 = (const float*)d_in[6];
    const float* Wc = (const float*)d_in[7];
    const float* bc = (const float*)d_in[8];
    float* out = (float*)d_out;

    char* ws = (char*)d_ws;
    size_t off = 0;
    auto alloc = [&](size_t bytes) { char* p = ws + off; off += (bytes + 255) & ~255ULL; return p; };
    float*  dinv     = (float*)alloc(NN * 4);
    int*    rowptr   = (int*)  alloc((NN + 1) * 4);
    int*    bsum     = (int*)  alloc(64 * 4);
    int2*   csr      = (int2*) alloc((size_t)NE * 8);   // {src, norm} interleaved
    ushort* Bf1      = (ushort*)alloc(16 * 8192 * 2);   // K=512 fragments (hi/lo)
    ushort* Bf2      = (ushort*)alloc(4 * 8192 * 2);    // K=128 fragments
    float*  P0       = (float*)alloc((size_t)NN * DH * 4);
    ushort* H2h      = (ushort*)alloc((size_t)NN * DH * 2);
    ushort* H2l      = (ushort*)alloc((size_t)NN * DH * 2);

    // setup-phase aliases into regions dead until mm1/agg1:
    uint* rank = (uint*)P0;                                  // dead once mm1 writes P0
    unsigned long long* packed = (unsigned long long*)H2h;   // dead once agg1 writes H2h

    init_packed_kernel<<<(NN + 255) / 256, 256, 0, stream>>>(packed, NN);
    deg_rank_kernel<<<(NE + 255) / 256, 256, 0, stream>>>(ei, ew, packed, rank, NE);
    unpack_kernel<<<(NN + 255) / 256, 256, 0, stream>>>(packed, dinv, NN);
    scan1_kernel<<<(NN + 1023) / 1024, 256, 0, stream>>>(packed, rowptr, bsum, NN);
    scan2_kernel<<<1, 64, 0, stream>>>(bsum, (NN + 1023) / 1024);
    scan3_kernel<<<(NN + 255) / 256, 256, 0, stream>>>(rowptr, bsum, NN);
    scatter_kernel<<<(NE + 255) / 256, 256, 0, stream>>>(ei, ew, dinv, rank, rowptr, csr, NE);
    prep_w_kernel<<<(16 * 8192 + 255) / 256, 256, 0, stream>>>(W1, Bf1, FIN, 16 * 8192);
    prep_w_kernel<<<(4 * 8192 + 255) / 256, 256, 0, stream>>>(W2, Bf2, DH, 4 * 8192);

    int mm_blocks = (NN + 127) / 128;   // 391

    // layer 1: h1 = x @ W1 (MFMA bf16x3, in-reg split of A), agg -> bf16 hi/lo
    mm_mfma_kernel<0><<<mm_blocks, 256, 0, stream>>>(x, nullptr, nullptr, Bf1, P0, NN, FIN, 512);
    agg_bf16_kernel<<<(NN * 64 + 255) / 256, 256, 0, stream>>>(P0, rowptr, csr, dinv, b1,
                                                               H2h, H2l, NN);
    // layer 2: h2 = h1 @ W2 (A pre-split), fused agg+relu+classifier
    mm_mfma_kernel<1><<<mm_blocks, 256, 0, stream>>>(nullptr, H2h, H2l, Bf2, P0, NN, DH, 128);
    agg_cls_kernel<<<(NN * 64 + 255) / 256, 256, 0, stream>>>(P0, rowptr, csr, dinv, b2,
                                                              Wc, bc, out, NN);
}

// Round 12
// 388.227 us; speedup vs baseline: 1.0731x; 1.0731x over previous
//
#include <hip/hip_runtime.h>

#define NN 50000
#define NE 800000
#define FIN 500
#define DH 128
#define NC 10

typedef __attribute__((ext_vector_type(8))) short short8v;   // 8 bf16 (4 VGPRs)
typedef __attribute__((ext_vector_type(4))) float float4v;   // MFMA C/D
typedef __attribute__((ext_vector_type(4))) int int4v;

__device__ __forceinline__ ushort f32_bf16_rne(float f) {
    uint u = __float_as_uint(f);
    uint r = u + 0x7FFFu + ((u >> 16) & 1u);
    return (ushort)(r >> 16);
}

// split 8 f32 -> bf16 hi + bf16 lo via v_cvt_pk_bf16_f32 (RNE, 2 elems/inst)
__device__ __forceinline__ void split8(const float f[8], short8v& hi, short8v& lo) {
    int4v hw, lw;
    #pragma unroll
    for (int p = 0; p < 4; ++p) {
        float x0 = f[2 * p], x1 = f[2 * p + 1];
        uint h;
        asm("v_cvt_pk_bf16_f32 %0, %1, %2" : "=v"(h) : "v"(x0), "v"(x1));
        float r0 = x0 - __uint_as_float(h << 16);
        float r1 = x1 - __uint_as_float(h & 0xFFFF0000u);
        uint l;
        asm("v_cvt_pk_bf16_f32 %0, %1, %2" : "=v"(l) : "v"(r0), "v"(r1));
        hw[p] = (int)h; lw[p] = (int)l;
    }
    hi = __builtin_bit_cast(short8v, hw);
    lo = __builtin_bit_cast(short8v, lw);
}

// ---------------- setup kernels ----------------

__global__ void init_packed_kernel(unsigned long long* __restrict__ packed, int n) {
    int i = blockIdx.x * blockDim.x + threadIdx.x;
    if (i < n) packed[i] = 0ULL;
}

// ONE 64-bit atomic per edge: high word = incoming-edge count, low word = sum of
// w in 24-bit fixed point. Returned old high word = edge's rank within dst row.
__global__ void deg_rank_kernel(const int* __restrict__ ei, const float* __restrict__ w,
                                unsigned long long* __restrict__ packed,
                                uint* __restrict__ rank, int e) {
    int i = blockIdx.x * blockDim.x + threadIdx.x;
    if (i < e) {
        int d = ei[NE + i];
        uint fx = (uint)(w[i] * 16777216.0f + 0.5f);
        unsigned long long old = atomicAdd(&packed[d], (1ULL << 32) | (unsigned long long)fx);
        rank[i] = (uint)(old >> 32);
    }
}

// ---- scan over counts (high words) -> rowptr (exclusive); also emits dinv ----
__global__ void scan1_kernel(const unsigned long long* __restrict__ packed,
                             int* __restrict__ rp, int* __restrict__ bsum,
                             float* __restrict__ dinv, int n) {
    __shared__ int sw[4];
    int t = threadIdx.x, lane = t & 63, w = t >> 6;
    int base = blockIdx.x * 1024 + t * 4;
    unsigned long long p0 = (base + 0 < n) ? packed[base + 0] : 0ULL;
    unsigned long long p1 = (base + 1 < n) ? packed[base + 1] : 0ULL;
    unsigned long long p2 = (base + 2 < n) ? packed[base + 2] : 0ULL;
    unsigned long long p3 = (base + 3 < n) ? packed[base + 3] : 0ULL;
    int c0 = (int)(p0 >> 32), c1 = (int)(p1 >> 32), c2 = (int)(p2 >> 32), c3 = (int)(p3 >> 32);
    const float inv24 = 1.0f / 16777216.0f;
    if (base + 0 < n) dinv[base + 0] = rsqrtf(1.0f + (float)(uint)p0 * inv24);
    if (base + 1 < n) dinv[base + 1] = rsqrtf(1.0f + (float)(uint)p1 * inv24);
    if (base + 2 < n) dinv[base + 2] = rsqrtf(1.0f + (float)(uint)p2 * inv24);
    if (base + 3 < n) dinv[base + 3] = rsqrtf(1.0f + (float)(uint)p3 * inv24);
    int s0 = c0, s1 = s0 + c1, s2 = s1 + c2, s3 = s2 + c3;
    int x = s3;
    #pragma unroll
    for (int off = 1; off < 64; off <<= 1) {
        int y = __shfl_up(x, off, 64);
        if (lane >= off) x += y;
    }
    if (lane == 63) sw[w] = x;
    __syncthreads();
    int woff = 0;
    for (int j = 0; j < w; ++j) woff += sw[j];
    int excl = woff + x - s3;
    if (base + 0 < n) rp[base + 0] = excl;
    if (base + 1 < n) rp[base + 1] = excl + s0;
    if (base + 2 < n) rp[base + 2] = excl + s1;
    if (base + 3 < n) rp[base + 3] = excl + s2;
    if (t == 255) bsum[blockIdx.x] = woff + x;
}

__global__ void scan2_kernel(int* __restrict__ bsum, int nb) {
    int lane = threadIdx.x;
    int v = (lane < nb) ? bsum[lane] : 0;
    int x = v;
    #pragma unroll
    for (int off = 1; off < 64; off <<= 1) {
        int y = __shfl_up(x, off, 64);
        if (lane >= off) x += y;
    }
    if (lane < nb) bsum[lane] = x - v;
}

__global__ void scan3_kernel(int* __restrict__ rp, const int* __restrict__ bsum, int n) {
    int i = blockIdx.x * blockDim.x + threadIdx.x;
    if (i < n) rp[i] = rp[i] + bsum[i >> 10];
    if (i == 0) rp[n] = NE;
}

// atomic-free scatter: pos = rowptr[d] + rank; ONE 8B store per edge (int2{src,norm})
__global__ void scatter_kernel(const int* __restrict__ ei, const float* __restrict__ w,
                               const float* __restrict__ dinv, const uint* __restrict__ rank,
                               const int* __restrict__ rowptr,
                               int2* __restrict__ csr, int e) {
    int i = blockIdx.x * blockDim.x + threadIdx.x;
    if (i < e) {
        int s = ei[i];
        int d = ei[NE + i];
        int pos = rowptr[d] + (int)rank[i];
        float nm = dinv[s] * w[i] * dinv[d];
        csr[pos] = make_int2(s, __float_as_int(nm));
    }
}

// ---- prep: W[K][128] -> Bf in MFMA fragment order ----
__global__ void prep_w_kernel(const float* __restrict__ W, ushort* __restrict__ Bf,
                              int K, int total) {
    int idx = blockIdx.x * blockDim.x + threadIdx.x;
    if (idx >= total) return;
    int j = idx & 7;
    int lane = (idx >> 3) & 63;
    int h = (idx >> 9) & 1;
    int c = (idx >> 10) & 7;
    int ks = idx >> 13;
    int k = ks * 32 + (lane >> 4) * 8 + j;
    int col = c * 16 + (lane & 15);
    float v = (k < K) ? W[k * DH + col] : 0.f;
    ushort hi = f32_bf16_rne(v);
    ushort o;
    if (h == 0) o = hi;
    else {
        float hf = __uint_as_float((uint)hi << 16);
        o = f32_bf16_rne(v - hf);
    }
    Bf[idx] = o;
}

// ---------------- MFMA matmul (unchanged from round 8) ----------------

__device__ __forceinline__ void load_split_row(const float* __restrict__ Af, int row, int kb,
                                               int K, bool last, short8v& hi, short8v& lo) {
    float f[8];
    if (last && kb + 8 > K) {
        #pragma unroll
        for (int j = 0; j < 8; ++j)
            f[j] = (kb + j < K) ? Af[(size_t)row * K + kb + j] : 0.f;
    } else {
        float4 t0 = *(const float4*)(Af + (size_t)row * K + kb);
        float4 t1 = *(const float4*)(Af + (size_t)row * K + kb + 4);
        f[0] = t0.x; f[1] = t0.y; f[2] = t0.z; f[3] = t0.w;
        f[4] = t1.x; f[5] = t1.y; f[6] = t1.z; f[7] = t1.w;
    }
    split8(f, hi, lo);
}

template<int A_SPLIT>
__global__ __launch_bounds__(256)
void mm_mfma_kernel(const float* __restrict__ Af,
                    const ushort* __restrict__ Ah, const ushort* __restrict__ Al,
                    const ushort* __restrict__ Bf,
                    float* __restrict__ C, int M, int K, int Kp) {
    __shared__ ushort Bs[4 * 8192];
    const int t = threadIdx.x;
    const int lane = t & 63, wid = t >> 6;
    const int lrow = lane & 15, lk = lane >> 4;
    const int row0 = blockIdx.x * 128 + wid * 32;
    const int nchunks = Kp >> 7;

    float4v acc0[8], acc1[8];
    #pragma unroll
    for (int c = 0; c < 8; ++c) {
        acc0[c] = (float4v){0.f, 0.f, 0.f, 0.f};
        acc1[c] = (float4v){0.f, 0.f, 0.f, 0.f};
    }

    int ar0 = row0 + lrow;       if (ar0 > M - 1) ar0 = M - 1;
    int ar1 = row0 + 16 + lrow;  if (ar1 > M - 1) ar1 = M - 1;
    const bool l0 = (ar0 == M - 1), l1 = (ar1 == M - 1);

    for (int kc = 0; kc < nchunks; ++kc) {
        const uint4* src = (const uint4*)(Bf + (size_t)kc * 32768);
        #pragma unroll
        for (int i = 0; i < 16; ++i) {
            int slot = i * 256 + t;
            *(uint4*)&Bs[slot * 8] = src[slot];
        }
        __syncthreads();
        #pragma unroll
        for (int ksl = 0; ksl < 4; ++ksl) {
            const int kb = (kc * 4 + ksl) * 32 + lk * 8;
            short8v a0h, a0l, a1h, a1l;
            if (A_SPLIT) {
                a0h = *(const short8v*)(Ah + (size_t)ar0 * Kp + kb);
                a0l = *(const short8v*)(Al + (size_t)ar0 * Kp + kb);
                a1h = *(const short8v*)(Ah + (size_t)ar1 * Kp + kb);
                a1l = *(const short8v*)(Al + (size_t)ar1 * Kp + kb);
            } else {
                load_split_row(Af, ar0, kb, K, l0, a0h, a0l);
                load_split_row(Af, ar1, kb, K, l1, a1h, a1l);
            }
            const ushort* bp = &Bs[ksl * 8192 + lane * 8];
            #pragma unroll
            for (int c = 0; c < 8; ++c) {
                short8v bh = *(const short8v*)(bp + c * 1024);
                short8v bl = *(const short8v*)(bp + c * 1024 + 512);
                acc0[c] = __builtin_amdgcn_mfma_f32_16x16x32_bf16(a0h, bh, acc0[c], 0, 0, 0);
                acc0[c] = __builtin_amdgcn_mfma_f32_16x16x32_bf16(a0h, bl, acc0[c], 0, 0, 0);
                acc0[c] = __builtin_amdgcn_mfma_f32_16x16x32_bf16(a0l, bh, acc0[c], 0, 0, 0);
                acc1[c] = __builtin_amdgcn_mfma_f32_16x16x32_bf16(a1h, bh, acc1[c], 0, 0, 0);
                acc1[c] = __builtin_amdgcn_mfma_f32_16x16x32_bf16(a1h, bl, acc1[c], 0, 0, 0);
                acc1[c] = __builtin_amdgcn_mfma_f32_16x16x32_bf16(a1l, bh, acc1[c], 0, 0, 0);
            }
        }
        __syncthreads();
    }
    #pragma unroll
    for (int c = 0; c < 8; ++c) {
        #pragma unroll
        for (int j = 0; j < 4; ++j) {
            int r0 = row0 + lk * 4 + j;
            int r1 = row0 + 16 + lk * 4 + j;
            if (r0 < M) C[(size_t)r0 * DH + c * 16 + lrow] = acc0[c][j];
            if (r1 < M) C[(size_t)r1 * DH + c * 16 + lrow] = acc1[c][j];
        }
    }
}

// ---------------- aggregation: wave per node, float2 per lane (round-8 shape) --
// Unmasked unroll-8 main + unroll-4 mid + scalar tail (<=3). No shfl, no LDS.

#define AGG_BODY                                                                  \
    int node = (blockIdx.x * 256 + threadIdx.x) >> 6;                             \
    if (node >= n) return;                                                        \
    int lane = threadIdx.x & 63;                                                  \
    float di = dinv[node];                                                        \
    float2 hv = *(const float2*)&h[(size_t)node * DH + lane * 2];                 \
    float ax = di * di * hv.x, ay = di * di * hv.y;                               \
    int e = rowptr[node], e1 = rowptr[node + 1];                                  \
    for (; e + 8 <= e1; e += 8) {                                                 \
        int2 m[8];                                                                \
        _Pragma("unroll")                                                         \
        for (int j = 0; j < 8; ++j) m[j] = csr[e + j];                            \
        float2 v[8];                                                              \
        _Pragma("unroll")                                                         \
        for (int j = 0; j < 8; ++j)                                               \
            v[j] = *(const float2*)&h[(size_t)m[j].x * DH + lane * 2];            \
        _Pragma("unroll")                                                         \
        for (int j = 0; j < 8; ++j) {                                             \
            float nm = __int_as_float(m[j].y);                                    \
            ax = fmaf(nm, v[j].x, ax); ay = fmaf(nm, v[j].y, ay);                 \
        }                                                                         \
    }                                                                             \
    if (e + 4 <= e1) {                                                            \
        int2 m[4];                                                                \
        _Pragma("unroll")                                                         \
        for (int j = 0; j < 4; ++j) m[j] = csr[e + j];                            \
        float2 v[4];                                                              \
        _Pragma("unroll")                                                         \
        for (int j = 0; j < 4; ++j)                                               \
            v[j] = *(const float2*)&h[(size_t)m[j].x * DH + lane * 2];            \
        _Pragma("unroll")                                                         \
        for (int j = 0; j < 4; ++j) {                                             \
            float nm = __int_as_float(m[j].y);                                    \
            ax = fmaf(nm, v[j].x, ax); ay = fmaf(nm, v[j].y, ay);                 \
        }                                                                         \
        e += 4;                                                                   \
    }                                                                             \
    for (; e < e1; ++e) {                                                         \
        int2 pr = csr[e];                                                         \
        float nm = __int_as_float(pr.y);                                          \
        float2 v = *(const float2*)&h[(size_t)pr.x * DH + lane * 2];              \
        ax = fmaf(nm, v.x, ax); ay = fmaf(nm, v.y, ay);                           \
    }                                                                             \
    float hx = fmaxf(ax + bias[lane * 2], 0.f);                                   \
    float hy = fmaxf(ay + bias[lane * 2 + 1], 0.f);

__global__ __launch_bounds__(256)
void agg_bf16_kernel(const float* __restrict__ h, const int* __restrict__ rowptr,
                     const int2* __restrict__ csr,
                     const float* __restrict__ dinv, const float* __restrict__ bias,
                     ushort* __restrict__ oh, ushort* __restrict__ ol, int n) {
    AGG_BODY
    ushort hxh = f32_bf16_rne(hx);
    ushort hyh = f32_bf16_rne(hy);
    ushort hxl = f32_bf16_rne(hx - __uint_as_float((uint)hxh << 16));
    ushort hyl = f32_bf16_rne(hy - __uint_as_float((uint)hyh << 16));
    *(ushort2*)&oh[(size_t)node * DH + lane * 2] = make_ushort2(hxh, hyh);
    *(ushort2*)&ol[(size_t)node * DH + lane * 2] = make_ushort2(hxl, hyl);
}

// agg + classifier fused
__global__ __launch_bounds__(256)
void agg_cls_kernel(const float* __restrict__ h, const int* __restrict__ rowptr,
                    const int2* __restrict__ csr,
                    const float* __restrict__ dinv, const float* __restrict__ bias,
                    const float* __restrict__ Wc, const float* __restrict__ bc,
                    float* __restrict__ out, int n) {
    AGG_BODY
    float myv = 0.f;
    #pragma unroll
    for (int c = 0; c < NC; ++c) {
        float p = hx * Wc[(2 * lane) * NC + c] + hy * Wc[(2 * lane + 1) * NC + c];
        p += __shfl_xor(p, 32, 64);
        p += __shfl_xor(p, 16, 64);
        p += __shfl_xor(p, 8, 64);
        p += __shfl_xor(p, 4, 64);
        p += __shfl_xor(p, 2, 64);
        p += __shfl_xor(p, 1, 64);
        if (lane == c) myv = p;
    }
    if (lane < NC) out[(size_t)node * NC + lane] = myv + bc[lane];
}

// ---------------- launch ----------------

extern "C" void kernel_launch(void* const* d_in, const int* in_sizes, int n_in,
                              void* d_out, int out_size, void* d_ws, size_t ws_size,
                              hipStream_t stream) {
    const float* x  = (const float*)d_in[0];
    const int*   ei = (const int*)d_in[1];
    const float* ew = (const float*)d_in[2];
    const float* W1 = (const float*)d_in[3];
    const float* b1 = (const float*)d_in[4];
    const float* W2 = (const float*)d_in[5];
    const float* b2 = (const float*)d_in[6];
    const float* Wc = (const float*)d_in[7];
    const float* bc = (const float*)d_in[8];
    float* out = (float*)d_out;

    char* ws = (char*)d_ws;
    size_t off = 0;
    auto alloc = [&](size_t bytes) { char* p = ws + off; off += (bytes + 255) & ~255ULL; return p; };
    float*  dinv     = (float*)alloc(NN * 4);
    int*    rowptr   = (int*)  alloc((NN + 1) * 4);
    int*    bsum     = (int*)  alloc(64 * 4);
    int2*   csr      = (int2*) alloc((size_t)NE * 8);   // {src, norm} interleaved
    ushort* Bf1      = (ushort*)alloc(16 * 8192 * 2);   // K=512 fragments (hi/lo)
    ushort* Bf2      = (ushort*)alloc(4 * 8192 * 2);    // K=128 fragments
    float*  P0       = (float*)alloc((size_t)NN * DH * 4);
    ushort* H2h      = (ushort*)alloc((size_t)NN * DH * 2);
    ushort* H2l      = (ushort*)alloc((size_t)NN * DH * 2);

    // setup-phase aliases into regions dead until mm1/agg1:
    uint* rank = (uint*)P0;                                  // dead once mm1 writes P0
    unsigned long long* packed = (unsigned long long*)H2h;   // dead once agg1 writes H2h

    init_packed_kernel<<<(NN + 255) / 256, 256, 0, stream>>>(packed, NN);
    deg_rank_kernel<<<(NE + 255) / 256, 256, 0, stream>>>(ei, ew, packed, rank, NE);
    scan1_kernel<<<(NN + 1023) / 1024, 256, 0, stream>>>(packed, rowptr, bsum, dinv, NN);
    scan2_kernel<<<1, 64, 0, stream>>>(bsum, (NN + 1023) / 1024);
    scan3_kernel<<<(NN + 255) / 256, 256, 0, stream>>>(rowptr, bsum, NN);
    scatter_kernel<<<(NE + 255) / 256, 256, 0, stream>>>(ei, ew, dinv, rank, rowptr, csr, NE);
    prep_w_kernel<<<(16 * 8192 + 255) / 256, 256, 0, stream>>>(W1, Bf1, FIN, 16 * 8192);
    prep_w_kernel<<<(4 * 8192 + 255) / 256, 256, 0, stream>>>(W2, Bf2, DH, 4 * 8192);

    int mm_blocks = (NN + 127) / 128;   // 391

    // layer 1: h1 = x @ W1 (MFMA bf16x3, in-reg split of A), agg -> bf16 hi/lo
    mm_mfma_kernel<0><<<mm_blocks, 256, 0, stream>>>(x, nullptr, nullptr, Bf1, P0, NN, FIN, 512);
    agg_bf16_kernel<<<(NN * 64 + 255) / 256, 256, 0, stream>>>(P0, rowptr, csr, dinv, b1,
                                                               H2h, H2l, NN);
    // layer 2: h2 = h1 @ W2 (A pre-split), fused agg+relu+classifier
    mm_mfma_kernel<1><<<mm_blocks, 256, 0, stream>>>(nullptr, H2h, H2l, Bf2, P0, NN, DH, 128);
    agg_cls_kernel<<<(NN * 64 + 255) / 256, 256, 0, stream>>>(P0, rowptr, csr, dinv, b2,
                                                              Wc, bc, out, NN);
}